// Round 3
// baseline (478.289 us; speedup 1.0000x reference)
//
#include <hip/hip_runtime.h>
#include <hip/hip_bf16.h>

constexpr int Bb = 4, Ss = 1024, Dd = 1024, Hh = 16;

typedef __attribute__((ext_vector_type(8))) short short8;
typedef __attribute__((ext_vector_type(4))) float f32x4;

static __device__ __forceinline__ ushort f2bf(float f) {
  union { __hip_bfloat16 h; ushort u; } cv;
  cv.h = __float2bfloat16(f);
  return cv.u;
}

// async global->LDS, 16B per lane. LDS dest must be wave-uniform base.
static __device__ __forceinline__ void gl_lds16(const ushort* g, ushort* l) {
  __builtin_amdgcn_global_load_lds(
      (const __attribute__((address_space(1))) void*)g,
      (__attribute__((address_space(3))) void*)l, 16, 0, 0);
}

// ---------------------------------------------------------------------------
// elementwise fp32 -> bf16 cast, 4 elems/thread
// ---------------------------------------------------------------------------
__global__ __launch_bounds__(256) void cast_f32_bf16(
    const float* __restrict__ in, ushort* __restrict__ out) {
  const int i = (blockIdx.x * 256 + threadIdx.x) * 4;
  const float4 v = *(const float4*)&in[i];
  ushort4 o;
  o.x = f2bf(v.x); o.y = f2bf(v.y); o.z = f2bf(v.z); o.w = f2bf(v.w);
  *(ushort4*)&out[i] = o;
}

// ---------------------------------------------------------------------------
// fp32 [R][C] -> bf16 [C][R]  (32x32 LDS tile transpose)
// ---------------------------------------------------------------------------
__global__ __launch_bounds__(256) void transpose_cast(
    const float* __restrict__ in, ushort* __restrict__ out, int R, int C) {
  __shared__ float T[32][33];
  const int c0 = blockIdx.x * 32, r0 = blockIdx.y * 32;
  const int t = threadIdx.x;
  const int r = t >> 3, c4 = (t & 7) * 4;
  const float4 v = *(const float4*)&in[(size_t)(r0 + r) * C + c0 + c4];
  T[r][c4 + 0] = v.x; T[r][c4 + 1] = v.y;
  T[r][c4 + 2] = v.z; T[r][c4 + 3] = v.w;
  __syncthreads();
  const int cc = t >> 3, rr4 = (t & 7) * 4;
  ushort4 o;
  o.x = f2bf(T[rr4 + 0][cc]); o.y = f2bf(T[rr4 + 1][cc]);
  o.z = f2bf(T[rr4 + 2][cc]); o.w = f2bf(T[rr4 + 3][cc]);
  *(ushort4*)&out[(size_t)(c0 + cc) * R + r0 + rr4] = o;
}

// ---------------------------------------------------------------------------
// bf16 GEMM (m97 structure): C[M][N] = A[M][K] * Bt[N][K]^T + bias
// global_load_lds width=16 staging into LINEAR LDS (LDK=32, no pad).
// XCD-aware chunked block swizzle (grid count divisible by 8).
// ---------------------------------------------------------------------------
template <int BM, int BN, bool OUT_BF16>
__global__ __launch_bounds__(256) void gemm_bt(
    const ushort* __restrict__ A, const ushort* __restrict__ Bt,
    const float* __restrict__ bias, void* __restrict__ Cout,
    int M, int N, int K) {
  constexpr int TM = BM / 32, TN = BN / 32;
  __shared__ ushort As[BM * 32];
  __shared__ ushort Bs[BN * 32];
  const int tid = threadIdx.x;
  const int wv = tid >> 6, lane = tid & 63;
  const int l15 = lane & 15, quad = lane >> 4;
  const int ln4 = lane >> 2, kp = (lane & 3) * 8;

  // XCD swizzle: consecutive linear ids per XCD -> A-panel reuse in its L2
  const int nwg = gridDim.x * gridDim.y;
  const int f = blockIdx.y * gridDim.x + blockIdx.x;
  const int cpx = nwg >> 3;
  const int swz = (f & 7) * cpx + (f >> 3);
  const int bx = swz % gridDim.x, by = swz / gridDim.x;
  const int m0 = by * BM, n0 = bx * BN;
  const int wrow = (wv >> 1) * (BM / 2), wcol = (wv & 1) * (BN / 2);

  const ushort* Arow = &A[(size_t)(m0 + wv * 16 + ln4) * K + kp];
  const ushort* Brow = &Bt[(size_t)(n0 + wv * 16 + ln4) * K + kp];
  ushort* As_base = &As[wv * 512];
  ushort* Bs_base = &Bs[wv * 512];

  f32x4 acc[TM][TN] = {};

  for (int k0 = 0; k0 < K; k0 += 32) {
#pragma unroll
    for (int u = 0; u < BM / 64; u++)
      gl_lds16(Arow + (size_t)u * 64 * K + k0, As_base + u * 2048);
#pragma unroll
    for (int u = 0; u < BN / 64; u++)
      gl_lds16(Brow + (size_t)u * 64 * K + k0, Bs_base + u * 2048);
    __syncthreads();  // drains vmcnt (global_load_lds) + barrier
    short8 af[TM], bfr[TN];
#pragma unroll
    for (int i = 0; i < TM; i++)
      af[i] = *(const short8*)&As[(wrow + i * 16 + l15) * 32 + quad * 8];
#pragma unroll
    for (int j = 0; j < TN; j++)
      bfr[j] = *(const short8*)&Bs[(wcol + j * 16 + l15) * 32 + quad * 8];
#pragma unroll
    for (int i = 0; i < TM; i++)
#pragma unroll
      for (int j = 0; j < TN; j++)
        acc[i][j] = __builtin_amdgcn_mfma_f32_16x16x32_bf16(af[i], bfr[j],
                                                            acc[i][j], 0, 0, 0);
    __syncthreads();
  }

#pragma unroll
  for (int j = 0; j < TN; j++) {
    const int col = n0 + wcol + j * 16 + l15;
    const float bv = bias[col];
#pragma unroll
    for (int i = 0; i < TM; i++) {
#pragma unroll
      for (int r = 0; r < 4; r++) {
        const int row = m0 + wrow + i * 16 + quad * 4 + r;
        const float v = acc[i][j][r] + bv;
        if (OUT_BF16)
          ((ushort*)Cout)[(size_t)row * N + col] = f2bf(v);
        else
          ((float*)Cout)[(size_t)row * N + col] = v;
      }
    }
  }
}

// ---------------------------------------------------------------------------
// V transpose: qkvb[b*S + j][2048 + h*64 + d] -> vt[bh][d][j]   (bf16)
// ---------------------------------------------------------------------------
__global__ __launch_bounds__(256) void vtrans(const ushort* __restrict__ qkvb,
                                              ushort* __restrict__ vt) {
  __shared__ ushort T[64 * 72];
  const int j0 = blockIdx.x * 64, bh = blockIdx.y;
  const int b = bh >> 4, h = bh & 15;
  const int t = threadIdx.x;
#pragma unroll
  for (int u = 0; u < 2; u++) {
    const int idx = t + 256 * u;
    const int row = idx >> 3, p = idx & 7;
    *(uint4*)&T[row * 72 + p * 8] = *(const uint4*)&qkvb[
        (size_t)((b << 10) + j0 + row) * 3072 + 2048 + h * 64 + p * 8];
  }
  __syncthreads();
#pragma unroll
  for (int u = 0; u < 2; u++) {
    const int idx = t + 256 * u;
    const int d = idx >> 3, p = idx & 7;
    ushort tmp[8];
#pragma unroll
    for (int kk = 0; kk < 8; kk++) tmp[kk] = T[(p * 8 + kk) * 72 + d];
    uint4 o;
    __builtin_memcpy(&o, tmp, 16);
    *(uint4*)&vt[((size_t)bh * 64 + d) * 1024 + j0 + p * 8] = o;
  }
}

// ---------------------------------------------------------------------------
// MFMA attention, QBLK=32. grid (S/32, B*H), block 512 = 8 waves.
// Each K-chunk gather now feeds 4 MFMAs (two 16-row q-halves) -> K gather
// instruction count and L2 K-traffic halve vs QBLK=16.
// XCD swizzle: 8 heads pinned per XCD (working set ~3 MB < 4 MB L2).
// ---------------------------------------------------------------------------
__global__ __launch_bounds__(512, 4) void attn_mfma(
    const ushort* __restrict__ qkvb,  // [4096][3072] bf16
    const ushort* __restrict__ vt,    // [64][64][1024] bf16
    const float* __restrict__ mask,   // [4][1024]
    float* __restrict__ w_out,        // [64][1024][1024]
    ushort* __restrict__ ab) {        // [4096][1024] bf16 merged heads
  constexpr int LDP = 1032;
  __shared__ ushort Ps[32 * LDP];   // probs bf16, 66 KB
  __shared__ float PM[32][8];       // per-row per-wave maxes
  __shared__ float PSum[32][8];     // per-row per-wave sums

  // XCD swizzle (grid 32 x 64 = 2048 blocks, x fastest; 2048 % 8 == 0)
  const int f = blockIdx.y * 32 + blockIdx.x;
  const int swz = (f & 7) * 256 + (f >> 3);
  const int qt = swz & 31, bh = swz >> 5;

  const int b = bh >> 4, h = bh & 15;
  const int q0 = qt * 32;
  const int tid = threadIdx.x;
  const int wv = tid >> 6, lane = tid & 63;
  const int l15 = lane & 15, quad = lane >> 4;

  // Q fragments for both 16-row halves (A operand: m = l15, k = quad*8+j)
  short8 qf0[2], qf1[2];
#pragma unroll
  for (int g = 0; g < 2; g++) {
    const size_t rowQ =
        (size_t)((b << 10) + q0 + g * 16 + l15) * 3072 + h * 64;
    qf0[g] = *(const short8*)&qkvb[rowQ + quad * 8];
    qf1[g] = *(const short8*)&qkvb[rowQ + 32 + quad * 8];
  }

  float sreg[2][8][4];

  // ---- scores: wave wv owns j-chunks (wv + 8i)*16 ----
#pragma unroll
  for (int i = 0; i < 8; i++) {
    const int j0 = (wv + 8 * i) * 16;
    const int col = j0 + l15;
    const float mv = mask[(b << 10) + col];
    if (j0 <= q0 + 31) {
      const size_t rowK =
          (size_t)((b << 10) + j0 + l15) * 3072 + 1024 + h * 64;
      const short8 kf0 = *(const short8*)&qkvb[rowK + quad * 8];
      const short8 kf1 = *(const short8*)&qkvb[rowK + 32 + quad * 8];
#pragma unroll
      for (int g = 0; g < 2; g++) {
        f32x4 c = {0.f, 0.f, 0.f, 0.f};
        c = __builtin_amdgcn_mfma_f32_16x16x32_bf16(qf0[g], kf0, c, 0, 0, 0);
        c = __builtin_amdgcn_mfma_f32_16x16x32_bf16(qf1[g], kf1, c, 0, 0, 0);
#pragma unroll
        for (int r = 0; r < 4; r++)
          sreg[g][i][r] =
              (col <= q0 + g * 16 + quad * 4 + r ? c[r] * 0.125f : -10000.0f) +
              mv;
      }
    } else {
#pragma unroll
      for (int g = 0; g < 2; g++)
#pragma unroll
        for (int r = 0; r < 4; r++) sreg[g][i][r] = -10000.0f + mv;
    }
  }

  // ---- row max: register -> intra-quad shuffle tree -> cross-wave LDS ----
#pragma unroll
  for (int g = 0; g < 2; g++)
#pragma unroll
    for (int r = 0; r < 4; r++) {
      float m = sreg[g][0][r];
#pragma unroll
      for (int i = 1; i < 8; i++) m = fmaxf(m, sreg[g][i][r]);
#pragma unroll
      for (int off = 1; off < 16; off <<= 1) m = fmaxf(m, __shfl_xor(m, off));
      if (l15 == 0) PM[g * 16 + quad * 4 + r][wv] = m;
    }
  __syncthreads();

  float mrow[2][4];
#pragma unroll
  for (int g = 0; g < 2; g++)
#pragma unroll
    for (int r = 0; r < 4; r++) {
      const f32x4 a = *(const f32x4*)&PM[g * 16 + quad * 4 + r][0];
      const f32x4 c = *(const f32x4*)&PM[g * 16 + quad * 4 + r][4];
      mrow[g][r] = fmaxf(fmaxf(fmaxf(a[0], a[1]), fmaxf(a[2], a[3])),
                         fmaxf(fmaxf(c[0], c[1]), fmaxf(c[2], c[3])));
    }

  // ---- exp (clamped) + row sum ----
  float psum[2][4] = {};
#pragma unroll
  for (int i = 0; i < 8; i++)
#pragma unroll
    for (int g = 0; g < 2; g++)
#pragma unroll
      for (int r = 0; r < 4; r++) {
        const float e = __expf(fminf(sreg[g][i][r] - mrow[g][r], 0.0f));
        sreg[g][i][r] = e;
        psum[g][r] += e;
      }
#pragma unroll
  for (int g = 0; g < 2; g++)
#pragma unroll
    for (int r = 0; r < 4; r++) {
      float s = psum[g][r];
#pragma unroll
      for (int off = 1; off < 16; off <<= 1) s += __shfl_xor(s, off);
      if (l15 == 0) PSum[g * 16 + quad * 4 + r][wv] = s;
    }
  __syncthreads();

  float inv4[2][4];
#pragma unroll
  for (int g = 0; g < 2; g++)
#pragma unroll
    for (int r = 0; r < 4; r++) {
      const f32x4 a = *(const f32x4*)&PSum[g * 16 + quad * 4 + r][0];
      const f32x4 c = *(const f32x4*)&PSum[g * 16 + quad * 4 + r][4];
      inv4[g][r] = 1.0f / fmaxf(a[0] + a[1] + a[2] + a[3] + c[0] + c[1] +
                                    c[2] + c[3],
                                1e-30f);
    }

  // ---- write w (fp32) + stash probs bf16 into LDS ----
#pragma unroll
  for (int i = 0; i < 8; i++) {
    const int j0 = (wv + 8 * i) * 16;
#pragma unroll
    for (int g = 0; g < 2; g++)
#pragma unroll
      for (int r = 0; r < 4; r++) {
        const int row = g * 16 + quad * 4 + r;
        const float p = sreg[g][i][r] * inv4[g][r];
        w_out[((size_t)(bh << 10) + q0 + row) * 1024 + j0 + l15] = p;
        Ps[row * LDP + j0 + l15] = f2bf(p);
      }
  }
  __syncthreads();

  // ---- PV: wave -> (d-block pw, q-half g). A = Ps rows, B = Vt[bh][d][key]
  const int pw = wv & 3, g = wv >> 2;
  f32x4 oacc = {0.f, 0.f, 0.f, 0.f};
  const int nch = (q0 + g * 16 + 47) >> 5;
  const ushort* vbase = vt + ((size_t)bh * 64 + pw * 16 + l15) * 1024;
  for (int c = 0; c < nch; c++) {
    const int k0 = c * 32;
    const short8 pf =
        *(const short8*)&Ps[(g * 16 + l15) * LDP + k0 + quad * 8];
    const short8 vf = *(const short8*)&vbase[k0 + quad * 8];
    oacc = __builtin_amdgcn_mfma_f32_16x16x32_bf16(pf, vf, oacc, 0, 0, 0);
  }
#pragma unroll
  for (int r = 0; r < 4; r++) {
    ab[(size_t)((b << 10) + q0 + g * 16 + quad * 4 + r) * 1024 + h * 64 +
       pw * 16 + l15] = f2bf(oacc[r]);
  }
}

// ---------------------------------------------------------------------------
extern "C" void kernel_launch(void* const* d_in, const int* in_sizes, int n_in,
                              void* d_out, int out_size, void* d_ws,
                              size_t ws_size, hipStream_t stream) {
  const float* x = (const float*)d_in[0];
  const float* mask = (const float*)d_in[1];
  const float* w_attn = (const float*)d_in[2];
  const float* b_attn = (const float*)d_in[3];
  const float* w_proj = (const float*)d_in[4];
  const float* b_proj = (const float*)d_in[5];

  float* out_a = (float*)d_out;                 // [4,1024,1024]
  float* out_w = out_a + (size_t)Bb * Ss * Dd;  // [4,16,1024,1024]

  char* ws = (char*)d_ws;
  ushort* xb   = (ushort*)(ws);                  //  8 MB
  ushort* wta  = (ushort*)(ws + (8u << 20));     //  6 MB
  ushort* wtp  = (ushort*)(ws + (14u << 20));    //  2 MB
  ushort* qkvb = (ushort*)(ws + (16u << 20));    // 24 MB
  ushort* vt   = (ushort*)(ws + (40u << 20));    //  8 MB
  ushort* ab   = (ushort*)(ws + (48u << 20));    //  8 MB

  cast_f32_bf16<<<(Bb * Ss * Dd) / 1024, 256, 0, stream>>>(x, xb);
  transpose_cast<<<dim3(3 * Dd / 32, Dd / 32), 256, 0, stream>>>(w_attn, wta,
                                                                 Dd, 3 * Dd);
  transpose_cast<<<dim3(Dd / 32, Dd / 32), 256, 0, stream>>>(w_proj, wtp, Dd,
                                                             Dd);
  gemm_bt<128, 128, true><<<dim3(3 * Dd / 128, Bb * Ss / 128), 256, 0,
                            stream>>>(xb, wta, b_attn, qkvb, Bb * Ss, 3 * Dd,
                                      Dd);
  vtrans<<<dim3(Ss / 64, Bb * Hh), 256, 0, stream>>>(qkvb, vt);
  attn_mfma<<<dim3(Ss / 32, Bb * Hh), 512, 0, stream>>>(qkvb, vt, mask, out_w,
                                                        ab);
  gemm_bt<128, 128, false><<<dim3(Dd / 128, Bb * Ss / 128), 256, 0, stream>>>(
      ab, wtp, b_proj, out_a, Bb * Ss, Dd, Dd);
}

// Round 5
// 466.279 us; speedup vs baseline: 1.0258x; 1.0258x over previous
//
#include <hip/hip_runtime.h>
#include <hip/hip_bf16.h>

constexpr int Bb = 4, Ss = 1024, Dd = 1024, Hh = 16;

typedef __attribute__((ext_vector_type(8))) short short8;
typedef __attribute__((ext_vector_type(4))) float f32x4;

static __device__ __forceinline__ ushort f2bf(float f) {
  union { __hip_bfloat16 h; ushort u; } cv;
  cv.h = __float2bfloat16(f);
  return cv.u;
}

// async global->LDS, 16B per lane. LDS dest must be wave-uniform base.
static __device__ __forceinline__ void gl_lds16(const ushort* g, ushort* l) {
  __builtin_amdgcn_global_load_lds(
      (const __attribute__((address_space(1))) void*)g,
      (__attribute__((address_space(3))) void*)l, 16, 0, 0);
}

// ---------------------------------------------------------------------------
// elementwise fp32 -> bf16 cast, 4 elems/thread
// ---------------------------------------------------------------------------
__global__ __launch_bounds__(256) void cast_f32_bf16(
    const float* __restrict__ in, ushort* __restrict__ out) {
  const int i = (blockIdx.x * 256 + threadIdx.x) * 4;
  const float4 v = *(const float4*)&in[i];
  ushort4 o;
  o.x = f2bf(v.x); o.y = f2bf(v.y); o.z = f2bf(v.z); o.w = f2bf(v.w);
  *(ushort4*)&out[i] = o;
}

// ---------------------------------------------------------------------------
// fp32 [R][C] -> bf16 [C][R]  (32x32 LDS tile transpose)
// ---------------------------------------------------------------------------
__global__ __launch_bounds__(256) void transpose_cast(
    const float* __restrict__ in, ushort* __restrict__ out, int R, int C) {
  __shared__ float T[32][33];
  const int c0 = blockIdx.x * 32, r0 = blockIdx.y * 32;
  const int t = threadIdx.x;
  const int r = t >> 3, c4 = (t & 7) * 4;
  const float4 v = *(const float4*)&in[(size_t)(r0 + r) * C + c0 + c4];
  T[r][c4 + 0] = v.x; T[r][c4 + 1] = v.y;
  T[r][c4 + 2] = v.z; T[r][c4 + 3] = v.w;
  __syncthreads();
  const int cc = t >> 3, rr4 = (t & 7) * 4;
  ushort4 o;
  o.x = f2bf(T[rr4 + 0][cc]); o.y = f2bf(T[rr4 + 1][cc]);
  o.z = f2bf(T[rr4 + 2][cc]); o.w = f2bf(T[rr4 + 3][cc]);
  *(ushort4*)&out[(size_t)(c0 + cc) * R + r0 + rr4] = o;
}

// ---------------------------------------------------------------------------
// bf16 GEMM (m97 structure): C[M][N] = A[M][K] * Bt[N][K]^T + bias
// global_load_lds width=16 staging into LINEAR LDS (LDK=32, no pad).
// (round-2 configuration: no block swizzle — operands are L2/L3 resident)
// ---------------------------------------------------------------------------
template <int BM, int BN, bool OUT_BF16>
__global__ __launch_bounds__(256) void gemm_bt(
    const ushort* __restrict__ A, const ushort* __restrict__ Bt,
    const float* __restrict__ bias, void* __restrict__ Cout,
    int M, int N, int K) {
  constexpr int TM = BM / 32, TN = BN / 32;
  __shared__ ushort As[BM * 32];
  __shared__ ushort Bs[BN * 32];
  const int tid = threadIdx.x;
  const int wv = tid >> 6, lane = tid & 63;
  const int l15 = lane & 15, quad = lane >> 4;
  const int ln4 = lane >> 2, kp = (lane & 3) * 8;
  const int m0 = blockIdx.y * BM, n0 = blockIdx.x * BN;
  const int wrow = (wv >> 1) * (BM / 2), wcol = (wv & 1) * (BN / 2);

  const ushort* Arow = &A[(size_t)(m0 + wv * 16 + ln4) * K + kp];
  const ushort* Brow = &Bt[(size_t)(n0 + wv * 16 + ln4) * K + kp];
  ushort* As_base = &As[wv * 512];
  ushort* Bs_base = &Bs[wv * 512];

  f32x4 acc[TM][TN] = {};

  for (int k0 = 0; k0 < K; k0 += 32) {
#pragma unroll
    for (int u = 0; u < BM / 64; u++)
      gl_lds16(Arow + (size_t)u * 64 * K + k0, As_base + u * 2048);
#pragma unroll
    for (int u = 0; u < BN / 64; u++)
      gl_lds16(Brow + (size_t)u * 64 * K + k0, Bs_base + u * 2048);
    __syncthreads();  // drains vmcnt (global_load_lds) + barrier
    short8 af[TM], bfr[TN];
#pragma unroll
    for (int i = 0; i < TM; i++)
      af[i] = *(const short8*)&As[(wrow + i * 16 + l15) * 32 + quad * 8];
#pragma unroll
    for (int j = 0; j < TN; j++)
      bfr[j] = *(const short8*)&Bs[(wcol + j * 16 + l15) * 32 + quad * 8];
#pragma unroll
    for (int i = 0; i < TM; i++)
#pragma unroll
      for (int j = 0; j < TN; j++)
        acc[i][j] = __builtin_amdgcn_mfma_f32_16x16x32_bf16(af[i], bfr[j],
                                                            acc[i][j], 0, 0, 0);
    __syncthreads();
  }

#pragma unroll
  for (int j = 0; j < TN; j++) {
    const int col = n0 + wcol + j * 16 + l15;
    const float bv = bias[col];
#pragma unroll
    for (int i = 0; i < TM; i++) {
#pragma unroll
      for (int r = 0; r < 4; r++) {
        const int row = m0 + wrow + i * 16 + quad * 4 + r;
        const float v = acc[i][j][r] + bv;
        if (OUT_BF16)
          ((ushort*)Cout)[(size_t)row * N + col] = f2bf(v);
        else
          ((float*)Cout)[(size_t)row * N + col] = v;
      }
    }
  }
}

// ---------------------------------------------------------------------------
// V transpose: qkvb[b*S + j][2048 + h*64 + d] -> vt[bh][d][j]   (bf16)
// ---------------------------------------------------------------------------
__global__ __launch_bounds__(256) void vtrans(const ushort* __restrict__ qkvb,
                                              ushort* __restrict__ vt) {
  __shared__ ushort T[64 * 72];
  const int j0 = blockIdx.x * 64, bh = blockIdx.y;
  const int b = bh >> 4, h = bh & 15;
  const int t = threadIdx.x;
#pragma unroll
  for (int u = 0; u < 2; u++) {
    const int idx = t + 256 * u;
    const int row = idx >> 3, p = idx & 7;
    *(uint4*)&T[row * 72 + p * 8] = *(const uint4*)&qkvb[
        (size_t)((b << 10) + j0 + row) * 3072 + 2048 + h * 64 + p * 8];
  }
  __syncthreads();
#pragma unroll
  for (int u = 0; u < 2; u++) {
    const int idx = t + 256 * u;
    const int d = idx >> 3, p = idx & 7;
    ushort tmp[8];
#pragma unroll
    for (int kk = 0; kk < 8; kk++) tmp[kk] = T[(p * 8 + kk) * 72 + d];
    uint4 o;
    __builtin_memcpy(&o, tmp, 16);
    *(uint4*)&vt[((size_t)bh * 64 + d) * 1024 + j0 + p * 8] = o;
  }
}

// ---------------------------------------------------------------------------
// MFMA attention (round-2 structure, QBLK=16, 4 waves) + causal dead-region
// fast path: chunks with j0 >= q0+16 have softmax output exactly 0.0f
// (exp underflow), so write zeros directly (vectorized float4 stores, no
// exp/max/sum work). XCD swizzle pins 8 heads per XCD (~3 MB < 4 MB L2).
// ---------------------------------------------------------------------------
__global__ __launch_bounds__(256) void attn_mfma(
    const ushort* __restrict__ qkvb,  // [4096][3072] bf16
    const ushort* __restrict__ vt,    // [64][64][1024] bf16
    const float* __restrict__ mask,   // [4][1024]
    float* __restrict__ w_out,        // [64][1024][1024]
    ushort* __restrict__ ab) {        // [4096][1024] bf16 merged heads
  constexpr int LDP = 1032;
  __shared__ ushort Ps[16 * LDP];   // probs bf16, 33 KB
  __shared__ float PM[16][4];       // per-row per-wave maxes
  __shared__ float PSum[16][4];     // per-row per-wave sums

  // XCD swizzle (grid 64 x 64 = 4096 blocks, x fastest in dispatch order)
  const int f = blockIdx.y * 64 + blockIdx.x;
  const int swz = (f & 7) * 512 + (f >> 3);
  const int qt = swz & 63, bh = swz >> 6;

  const int b = bh >> 4, h = bh & 15;
  const int q0 = qt * 16;
  const int tid = threadIdx.x;
  const int wv = tid >> 6, lane = tid & 63;
  const int l15 = lane & 15, quad = lane >> 4;

  // chunk i (j0 = (wv+4i)*16) is active iff j0 <= q0+15  <=>  wv+4i <= qt
  const int nact = (qt >= wv) ? ((qt - wv) >> 2) + 1 : 0;

  // ---- dead region: w and Ps are exactly zero; vectorized fill ----
  {
    const int zrow = quad * 4 + (l15 & 3);     // 0..15
    const int zc4 = (l15 >> 2) * 4;            // 0,4,8,12
    const float4 zf4 = {0.f, 0.f, 0.f, 0.f};
    const uint2 zu2 = {0u, 0u};
    float* wrow_p =
        &w_out[((size_t)(bh << 10) + q0 + zrow) * 1024 + zc4];
    for (int i = nact; i < 16; i++) {
      const int j0 = (wv + 4 * i) * 16;
      *(float4*)&wrow_p[j0] = zf4;                  // 16 B x 64 lanes = 1 KB
      *(uint2*)&Ps[zrow * LDP + j0 + zc4] = zu2;    // 8 B x 64 lanes = 512 B
    }
  }

  // Q fragments (A operand: m = l15, k = quad*8+j)
  const size_t rowQ = (size_t)((b << 10) + q0 + l15) * 3072 + h * 64;
  const short8 qf0 = *(const short8*)&qkvb[rowQ + quad * 8];
  const short8 qf1 = *(const short8*)&qkvb[rowQ + 32 + quad * 8];

  float sreg[16][4];

  // ---- scores (active chunks only; unrolled+guarded so sreg stays in regs)
#pragma unroll
  for (int i = 0; i < 16; i++) {
    if (i < nact) {
      const int j0 = (wv + 4 * i) * 16;
      const int col = j0 + l15;
      const float mv = mask[(b << 10) + col];
      const size_t rowK =
          (size_t)((b << 10) + j0 + l15) * 3072 + 1024 + h * 64;
      const short8 kf0 = *(const short8*)&qkvb[rowK + quad * 8];
      const short8 kf1 = *(const short8*)&qkvb[rowK + 32 + quad * 8];
      f32x4 c = {0.f, 0.f, 0.f, 0.f};
      c = __builtin_amdgcn_mfma_f32_16x16x32_bf16(qf0, kf0, c, 0, 0, 0);
      c = __builtin_amdgcn_mfma_f32_16x16x32_bf16(qf1, kf1, c, 0, 0, 0);
#pragma unroll
      for (int r = 0; r < 4; r++)
        sreg[i][r] =
            (col <= q0 + quad * 4 + r ? c[r] * 0.125f : -10000.0f) + mv;
    }
  }

  // ---- row max: register -> intra-quad shuffle tree -> cross-wave LDS ----
#pragma unroll
  for (int r = 0; r < 4; r++) {
    float m = -3e38f;
#pragma unroll
    for (int i = 0; i < 16; i++)
      if (i < nact) m = fmaxf(m, sreg[i][r]);
#pragma unroll
    for (int off = 1; off < 16; off <<= 1) m = fmaxf(m, __shfl_xor(m, off));
    if (l15 == 0) PM[quad * 4 + r][wv] = m;
  }
  __syncthreads();

  float mrow[4];
#pragma unroll
  for (int r = 0; r < 4; r++) {
    const f32x4 pm4 = *(const f32x4*)&PM[quad * 4 + r][0];
    mrow[r] = fmaxf(fmaxf(pm4[0], pm4[1]), fmaxf(pm4[2], pm4[3]));
  }

  // ---- exp (clamped) + row sum (active chunks only) ----
  float psum[4] = {0.f, 0.f, 0.f, 0.f};
#pragma unroll
  for (int i = 0; i < 16; i++)
    if (i < nact)
#pragma unroll
      for (int r = 0; r < 4; r++) {
        const float e = __expf(fminf(sreg[i][r] - mrow[r], 0.0f));
        sreg[i][r] = e;
        psum[r] += e;
      }
#pragma unroll
  for (int r = 0; r < 4; r++) {
    float s = psum[r];
#pragma unroll
    for (int off = 1; off < 16; off <<= 1) s += __shfl_xor(s, off);
    if (l15 == 0) PSum[quad * 4 + r][wv] = s;
  }
  __syncthreads();

  float inv4[4];
#pragma unroll
  for (int r = 0; r < 4; r++) {
    const f32x4 ps4 = *(const f32x4*)&PSum[quad * 4 + r][0];
    inv4[r] = 1.0f / fmaxf(ps4[0] + ps4[1] + ps4[2] + ps4[3], 1e-30f);
  }

  // ---- write w (fp32) + stash probs bf16 into LDS (active chunks only) ----
#pragma unroll
  for (int i = 0; i < 16; i++) {
    if (i < nact) {
      const int j0 = (wv + 4 * i) * 16;
#pragma unroll
      for (int r = 0; r < 4; r++) {
        const float p = sreg[i][r] * inv4[r];
        w_out[((size_t)(bh << 10) + q0 + quad * 4 + r) * 1024 + j0 + l15] = p;
        Ps[(quad * 4 + r) * LDP + j0 + l15] = f2bf(p);
      }
    }
  }
  __syncthreads();

  // ---- PV: A = Ps (A-frag m=l15, k=quad*8+j), B = Vt[bh][d][key] ----
  f32x4 oacc = {0.f, 0.f, 0.f, 0.f};
  const int nch = (q0 + 16 + 31) >> 5;
  const ushort* vbase = vt + ((size_t)bh * 64 + wv * 16 + l15) * 1024;
  for (int c = 0; c < nch; c++) {
    const int k0 = c * 32;
    const short8 pf = *(const short8*)&Ps[l15 * LDP + k0 + quad * 8];
    const short8 vf = *(const short8*)&vbase[k0 + quad * 8];
    oacc = __builtin_amdgcn_mfma_f32_16x16x32_bf16(pf, vf, oacc, 0, 0, 0);
  }
#pragma unroll
  for (int r = 0; r < 4; r++) {
    ab[(size_t)((b << 10) + q0 + quad * 4 + r) * 1024 + h * 64 + wv * 16 +
       l15] = f2bf(oacc[r]);
  }
}

// ---------------------------------------------------------------------------
extern "C" void kernel_launch(void* const* d_in, const int* in_sizes, int n_in,
                              void* d_out, int out_size, void* d_ws,
                              size_t ws_size, hipStream_t stream) {
  const float* x = (const float*)d_in[0];
  const float* mask = (const float*)d_in[1];
  const float* w_attn = (const float*)d_in[2];
  const float* b_attn = (const float*)d_in[3];
  const float* w_proj = (const float*)d_in[4];
  const float* b_proj = (const float*)d_in[5];

  float* out_a = (float*)d_out;                 // [4,1024,1024]
  float* out_w = out_a + (size_t)Bb * Ss * Dd;  // [4,16,1024,1024]

  char* ws = (char*)d_ws;
  ushort* xb   = (ushort*)(ws);                  //  8 MB
  ushort* wta  = (ushort*)(ws + (8u << 20));     //  6 MB
  ushort* wtp  = (ushort*)(ws + (14u << 20));    //  2 MB
  ushort* qkvb = (ushort*)(ws + (16u << 20));    // 24 MB
  ushort* vt   = (ushort*)(ws + (40u << 20));    //  8 MB
  ushort* ab   = (ushort*)(ws + (48u << 20));    //  8 MB

  cast_f32_bf16<<<(Bb * Ss * Dd) / 1024, 256, 0, stream>>>(x, xb);
  transpose_cast<<<dim3(3 * Dd / 32, Dd / 32), 256, 0, stream>>>(w_attn, wta,
                                                                 Dd, 3 * Dd);
  transpose_cast<<<dim3(Dd / 32, Dd / 32), 256, 0, stream>>>(w_proj, wtp, Dd,
                                                             Dd);
  gemm_bt<128, 128, true><<<dim3(3 * Dd / 128, Bb * Ss / 128), 256, 0,
                            stream>>>(xb, wta, b_attn, qkvb, Bb * Ss, 3 * Dd,
                                      Dd);
  vtrans<<<dim3(Ss / 64, Bb * Hh), 256, 0, stream>>>(qkvb, vt);
  attn_mfma<<<dim3(Ss / 16, Bb * Hh), 256, 0, stream>>>(qkvb, vt, mask, out_w,
                                                        ab);
  gemm_bt<128, 128, false><<<dim3(Dd / 128, Bb * Ss / 128), 256, 0, stream>>>(
      ab, wtp, b_proj, out_a, Bb * Ss, Dd, Dd);
}

// Round 6
// 448.409 us; speedup vs baseline: 1.0666x; 1.0399x over previous
//
#include <hip/hip_runtime.h>
#include <hip/hip_bf16.h>

constexpr int Bb = 4, Ss = 1024, Dd = 1024, Hh = 16;

typedef __attribute__((ext_vector_type(8))) short short8;
typedef __attribute__((ext_vector_type(4))) float f32x4;

static __device__ __forceinline__ ushort f2bf(float f) {
  union { __hip_bfloat16 h; ushort u; } cv;
  cv.h = __float2bfloat16(f);
  return cv.u;
}

// async global->LDS, 16B per lane. LDS dest must be wave-uniform base.
static __device__ __forceinline__ void gl_lds16(const ushort* g, ushort* l) {
  __builtin_amdgcn_global_load_lds(
      (const __attribute__((address_space(1))) void*)g,
      (__attribute__((address_space(3))) void*)l, 16, 0, 0);
}

// ---------------------------------------------------------------------------
// elementwise fp32 -> bf16 cast, 4 elems/thread
// ---------------------------------------------------------------------------
__global__ __launch_bounds__(256) void cast_f32_bf16(
    const float* __restrict__ in, ushort* __restrict__ out) {
  const int i = (blockIdx.x * 256 + threadIdx.x) * 4;
  const float4 v = *(const float4*)&in[i];
  ushort4 o;
  o.x = f2bf(v.x); o.y = f2bf(v.y); o.z = f2bf(v.z); o.w = f2bf(v.w);
  *(ushort4*)&out[i] = o;
}

// ---------------------------------------------------------------------------
// fp32 [R][C] -> bf16 [C][R]  (32x32 LDS tile transpose)
// ---------------------------------------------------------------------------
__global__ __launch_bounds__(256) void transpose_cast(
    const float* __restrict__ in, ushort* __restrict__ out, int R, int C) {
  __shared__ float T[32][33];
  const int c0 = blockIdx.x * 32, r0 = blockIdx.y * 32;
  const int t = threadIdx.x;
  const int r = t >> 3, c4 = (t & 7) * 4;
  const float4 v = *(const float4*)&in[(size_t)(r0 + r) * C + c0 + c4];
  T[r][c4 + 0] = v.x; T[r][c4 + 1] = v.y;
  T[r][c4 + 2] = v.z; T[r][c4 + 3] = v.w;
  __syncthreads();
  const int cc = t >> 3, rr4 = (t & 7) * 4;
  ushort4 o;
  o.x = f2bf(T[rr4 + 0][cc]); o.y = f2bf(T[rr4 + 1][cc]);
  o.z = f2bf(T[rr4 + 2][cc]); o.w = f2bf(T[rr4 + 3][cc]);
  *(ushort4*)&out[(size_t)(c0 + cc) * R + r0 + rr4] = o;
}

// ---------------------------------------------------------------------------
// bf16 GEMM (m97 structure): C[M][N] = A[M][K] * Bt[N][K]^T + bias
// global_load_lds width=16 staging into LINEAR LDS (LDK=32, no pad).
// ---------------------------------------------------------------------------
template <int BM, int BN, bool OUT_BF16>
__global__ __launch_bounds__(256) void gemm_bt(
    const ushort* __restrict__ A, const ushort* __restrict__ Bt,
    const float* __restrict__ bias, void* __restrict__ Cout,
    int M, int N, int K) {
  constexpr int TM = BM / 32, TN = BN / 32;
  __shared__ ushort As[BM * 32];
  __shared__ ushort Bs[BN * 32];
  const int tid = threadIdx.x;
  const int wv = tid >> 6, lane = tid & 63;
  const int l15 = lane & 15, quad = lane >> 4;
  const int ln4 = lane >> 2, kp = (lane & 3) * 8;
  const int m0 = blockIdx.y * BM, n0 = blockIdx.x * BN;
  const int wrow = (wv >> 1) * (BM / 2), wcol = (wv & 1) * (BN / 2);

  const ushort* Arow = &A[(size_t)(m0 + wv * 16 + ln4) * K + kp];
  const ushort* Brow = &Bt[(size_t)(n0 + wv * 16 + ln4) * K + kp];
  ushort* As_base = &As[wv * 512];
  ushort* Bs_base = &Bs[wv * 512];

  f32x4 acc[TM][TN] = {};

  for (int k0 = 0; k0 < K; k0 += 32) {
#pragma unroll
    for (int u = 0; u < BM / 64; u++)
      gl_lds16(Arow + (size_t)u * 64 * K + k0, As_base + u * 2048);
#pragma unroll
    for (int u = 0; u < BN / 64; u++)
      gl_lds16(Brow + (size_t)u * 64 * K + k0, Bs_base + u * 2048);
    __syncthreads();  // drains vmcnt (global_load_lds) + barrier
    short8 af[TM], bfr[TN];
#pragma unroll
    for (int i = 0; i < TM; i++)
      af[i] = *(const short8*)&As[(wrow + i * 16 + l15) * 32 + quad * 8];
#pragma unroll
    for (int j = 0; j < TN; j++)
      bfr[j] = *(const short8*)&Bs[(wcol + j * 16 + l15) * 32 + quad * 8];
#pragma unroll
    for (int i = 0; i < TM; i++)
#pragma unroll
      for (int j = 0; j < TN; j++)
        acc[i][j] = __builtin_amdgcn_mfma_f32_16x16x32_bf16(af[i], bfr[j],
                                                            acc[i][j], 0, 0, 0);
    __syncthreads();
  }

#pragma unroll
  for (int j = 0; j < TN; j++) {
    const int col = n0 + wcol + j * 16 + l15;
    const float bv = bias[col];
#pragma unroll
    for (int i = 0; i < TM; i++) {
#pragma unroll
      for (int r = 0; r < 4; r++) {
        const int row = m0 + wrow + i * 16 + quad * 4 + r;
        const float v = acc[i][j][r] + bv;
        if (OUT_BF16)
          ((ushort*)Cout)[(size_t)row * N + col] = f2bf(v);
        else
          ((float*)Cout)[(size_t)row * N + col] = v;
      }
    }
  }
}

// ---------------------------------------------------------------------------
// V transpose: qkvb[b*S + j][2048 + h*64 + d] -> vt[bh][d][j]   (bf16)
// ---------------------------------------------------------------------------
__global__ __launch_bounds__(256) void vtrans(const ushort* __restrict__ qkvb,
                                              ushort* __restrict__ vt) {
  __shared__ ushort T[64 * 72];
  const int j0 = blockIdx.x * 64, bh = blockIdx.y;
  const int b = bh >> 4, h = bh & 15;
  const int t = threadIdx.x;
#pragma unroll
  for (int u = 0; u < 2; u++) {
    const int idx = t + 256 * u;
    const int row = idx >> 3, p = idx & 7;
    *(uint4*)&T[row * 72 + p * 8] = *(const uint4*)&qkvb[
        (size_t)((b << 10) + j0 + row) * 3072 + 2048 + h * 64 + p * 8];
  }
  __syncthreads();
#pragma unroll
  for (int u = 0; u < 2; u++) {
    const int idx = t + 256 * u;
    const int d = idx >> 3, p = idx & 7;
    ushort tmp[8];
#pragma unroll
    for (int kk = 0; kk < 8; kk++) tmp[kk] = T[(p * 8 + kk) * 72 + d];
    uint4 o;
    __builtin_memcpy(&o, tmp, 16);
    *(uint4*)&vt[((size_t)bh * 64 + d) * 1024 + j0 + p * 8] = o;
  }
}

// ---------------------------------------------------------------------------
// MFMA attention (round-2 best-measured version). grid (S/16, B*H),
// block 256 = 4 waves. Shuffle-tree softmax reductions; XCD swizzle pins
// 8 heads per XCD (~3 MB working set < 4 MB per-XCD L2).
// ---------------------------------------------------------------------------
__global__ __launch_bounds__(256) void attn_mfma(
    const ushort* __restrict__ qkvb,  // [4096][3072] bf16
    const ushort* __restrict__ vt,    // [64][64][1024] bf16
    const float* __restrict__ mask,   // [4][1024]
    float* __restrict__ w_out,        // [64][1024][1024]
    ushort* __restrict__ ab) {        // [4096][1024] bf16 merged heads
  constexpr int LDP = 1032;
  __shared__ ushort Ps[16 * LDP];   // probs bf16, 33 KB
  __shared__ float PM[16][4];       // per-row per-wave maxes
  __shared__ float PSum[16][4];     // per-row per-wave sums

  // XCD swizzle (grid is 64 x 64 = 4096 blocks, x fastest in dispatch order)
  const int f = blockIdx.y * 64 + blockIdx.x;
  const int swz = (f & 7) * 512 + (f >> 3);
  const int qt = swz & 63, bh = swz >> 6;

  const int b = bh >> 4, h = bh & 15;
  const int q0 = qt * 16;
  const int tid = threadIdx.x;
  const int wv = tid >> 6, lane = tid & 63;
  const int l15 = lane & 15, quad = lane >> 4;

  // Q fragments (A operand: m = l15, k = quad*8+j)
  const size_t rowQ = (size_t)((b << 10) + q0 + l15) * 3072 + h * 64;
  const short8 qf0 = *(const short8*)&qkvb[rowQ + quad * 8];
  const short8 qf1 = *(const short8*)&qkvb[rowQ + 32 + quad * 8];

  float sreg[16][4];

  // ---- scores ----
#pragma unroll
  for (int i = 0; i < 16; i++) {
    const int j0 = (wv + 4 * i) * 16;
    const int col = j0 + l15;
    const float mv = mask[(b << 10) + col];
    if (j0 <= q0 + 15) {
      const size_t rowK = (size_t)((b << 10) + j0 + l15) * 3072 + 1024 + h * 64;
      const short8 kf0 = *(const short8*)&qkvb[rowK + quad * 8];
      const short8 kf1 = *(const short8*)&qkvb[rowK + 32 + quad * 8];
      f32x4 c = {0.f, 0.f, 0.f, 0.f};
      c = __builtin_amdgcn_mfma_f32_16x16x32_bf16(qf0, kf0, c, 0, 0, 0);
      c = __builtin_amdgcn_mfma_f32_16x16x32_bf16(qf1, kf1, c, 0, 0, 0);
#pragma unroll
      for (int r = 0; r < 4; r++)
        sreg[i][r] =
            (col <= q0 + quad * 4 + r ? c[r] * 0.125f : -10000.0f) + mv;
    } else {
#pragma unroll
      for (int r = 0; r < 4; r++) sreg[i][r] = -10000.0f + mv;
    }
  }

  // ---- row max: register -> intra-quad shuffle tree -> cross-wave LDS ----
#pragma unroll
  for (int r = 0; r < 4; r++) {
    float m = sreg[0][r];
#pragma unroll
    for (int i = 1; i < 16; i++) m = fmaxf(m, sreg[i][r]);
#pragma unroll
    for (int off = 1; off < 16; off <<= 1) m = fmaxf(m, __shfl_xor(m, off));
    if (l15 == 0) PM[quad * 4 + r][wv] = m;
  }
  __syncthreads();

  float mrow[4];
#pragma unroll
  for (int r = 0; r < 4; r++) {
    const f32x4 pm4 = *(const f32x4*)&PM[quad * 4 + r][0];
    mrow[r] = fmaxf(fmaxf(pm4[0], pm4[1]), fmaxf(pm4[2], pm4[3]));
  }

  // ---- exp (clamped) + row sum (same reduction shape) ----
  float psum[4] = {0.f, 0.f, 0.f, 0.f};
#pragma unroll
  for (int i = 0; i < 16; i++)
#pragma unroll
    for (int r = 0; r < 4; r++) {
      const float e = __expf(fminf(sreg[i][r] - mrow[r], 0.0f));
      sreg[i][r] = e;
      psum[r] += e;
    }
#pragma unroll
  for (int r = 0; r < 4; r++) {
    float s = psum[r];
#pragma unroll
    for (int off = 1; off < 16; off <<= 1) s += __shfl_xor(s, off);
    if (l15 == 0) PSum[quad * 4 + r][wv] = s;
  }
  __syncthreads();

  float inv4[4];
#pragma unroll
  for (int r = 0; r < 4; r++) {
    const f32x4 ps4 = *(const f32x4*)&PSum[quad * 4 + r][0];
    inv4[r] = 1.0f / fmaxf(ps4[0] + ps4[1] + ps4[2] + ps4[3], 1e-30f);
  }

  // ---- write w (fp32) + stash probs bf16 into LDS ----
#pragma unroll
  for (int i = 0; i < 16; i++) {
    const int j0 = (wv + 4 * i) * 16;
#pragma unroll
    for (int r = 0; r < 4; r++) {
      const float p = sreg[i][r] * inv4[r];
      w_out[((size_t)(bh << 10) + q0 + quad * 4 + r) * 1024 + j0 + l15] = p;
      Ps[(quad * 4 + r) * LDP + j0 + l15] = f2bf(p);
    }
  }
  __syncthreads();

  // ---- PV: A = Ps (A-frag m=l15, k=quad*8+j), B = Vt[bh][d][key] ----
  f32x4 oacc = {0.f, 0.f, 0.f, 0.f};
  const int nch = (q0 + 16 + 31) >> 5;
  const ushort* vbase = vt + ((size_t)bh * 64 + wv * 16 + l15) * 1024;
  for (int c = 0; c < nch; c++) {
    const int k0 = c * 32;
    const short8 pf = *(const short8*)&Ps[l15 * LDP + k0 + quad * 8];
    const short8 vf = *(const short8*)&vbase[k0 + quad * 8];
    oacc = __builtin_amdgcn_mfma_f32_16x16x32_bf16(pf, vf, oacc, 0, 0, 0);
  }
#pragma unroll
  for (int r = 0; r < 4; r++) {
    ab[(size_t)((b << 10) + q0 + quad * 4 + r) * 1024 + h * 64 + wv * 16 +
       l15] = f2bf(oacc[r]);
  }
}

// ---------------------------------------------------------------------------
extern "C" void kernel_launch(void* const* d_in, const int* in_sizes, int n_in,
                              void* d_out, int out_size, void* d_ws,
                              size_t ws_size, hipStream_t stream) {
  const float* x = (const float*)d_in[0];
  const float* mask = (const float*)d_in[1];
  const float* w_attn = (const float*)d_in[2];
  const float* b_attn = (const float*)d_in[3];
  const float* w_proj = (const float*)d_in[4];
  const float* b_proj = (const float*)d_in[5];

  float* out_a = (float*)d_out;                 // [4,1024,1024]
  float* out_w = out_a + (size_t)Bb * Ss * Dd;  // [4,16,1024,1024]

  char* ws = (char*)d_ws;
  ushort* xb   = (ushort*)(ws);                  //  8 MB
  ushort* wta  = (ushort*)(ws + (8u << 20));     //  6 MB
  ushort* wtp  = (ushort*)(ws + (14u << 20));    //  2 MB
  ushort* qkvb = (ushort*)(ws + (16u << 20));    // 24 MB
  ushort* vt   = (ushort*)(ws + (40u << 20));    //  8 MB
  ushort* ab   = (ushort*)(ws + (48u << 20));    //  8 MB

  cast_f32_bf16<<<(Bb * Ss * Dd) / 1024, 256, 0, stream>>>(x, xb);
  transpose_cast<<<dim3(3 * Dd / 32, Dd / 32), 256, 0, stream>>>(w_attn, wta,
                                                                 Dd, 3 * Dd);
  transpose_cast<<<dim3(Dd / 32, Dd / 32), 256, 0, stream>>>(w_proj, wtp, Dd,
                                                             Dd);
  gemm_bt<128, 128, true><<<dim3(3 * Dd / 128, Bb * Ss / 128), 256, 0,
                            stream>>>(xb, wta, b_attn, qkvb, Bb * Ss, 3 * Dd,
                                      Dd);
  vtrans<<<dim3(Ss / 64, Bb * Hh), 256, 0, stream>>>(qkvb, vt);
  attn_mfma<<<dim3(Ss / 16, Bb * Hh), 256, 0, stream>>>(qkvb, vt, mask, out_w,
                                                        ab);
  // proj: BN=64 -> grid 512 blocks = 2 blocks/CU (m114 implicit overlap
  // needs >=2 co-resident blocks; the 128x128 config was 1 block/CU with
  // fully-exposed barrier drains).
  gemm_bt<128, 64, false><<<dim3(Dd / 64, Bb * Ss / 128), 256, 0, stream>>>(
      ab, wtp, b_proj, out_a, Bb * Ss, Dd, Dd);
}

// Round 7
// 443.728 us; speedup vs baseline: 1.0779x; 1.0105x over previous
//
#include <hip/hip_runtime.h>
#include <hip/hip_bf16.h>

constexpr int Bb = 4, Ss = 1024, Dd = 1024, Hh = 16;

typedef __attribute__((ext_vector_type(8))) short short8;
typedef __attribute__((ext_vector_type(4))) float f32x4;

static __device__ __forceinline__ ushort f2bf(float f) {
  union { __hip_bfloat16 h; ushort u; } cv;
  cv.h = __float2bfloat16(f);
  return cv.u;
}

// async global->LDS, 16B per lane. LDS dest must be wave-uniform base.
static __device__ __forceinline__ void gl_lds16(const ushort* g, ushort* l) {
  __builtin_amdgcn_global_load_lds(
      (const __attribute__((address_space(1))) void*)g,
      (__attribute__((address_space(3))) void*)l, 16, 0, 0);
}

// ---------------------------------------------------------------------------
// elementwise fp32 -> bf16 cast, 4 elems/thread
// ---------------------------------------------------------------------------
__global__ __launch_bounds__(256) void cast_f32_bf16(
    const float* __restrict__ in, ushort* __restrict__ out) {
  const int i = (blockIdx.x * 256 + threadIdx.x) * 4;
  const float4 v = *(const float4*)&in[i];
  ushort4 o;
  o.x = f2bf(v.x); o.y = f2bf(v.y); o.z = f2bf(v.z); o.w = f2bf(v.w);
  *(ushort4*)&out[i] = o;
}

// ---------------------------------------------------------------------------
// fp32 [R][C] -> bf16 [C][R]  (32x32 LDS tile transpose)
// ---------------------------------------------------------------------------
__global__ __launch_bounds__(256) void transpose_cast(
    const float* __restrict__ in, ushort* __restrict__ out, int R, int C) {
  __shared__ float T[32][33];
  const int c0 = blockIdx.x * 32, r0 = blockIdx.y * 32;
  const int t = threadIdx.x;
  const int r = t >> 3, c4 = (t & 7) * 4;
  const float4 v = *(const float4*)&in[(size_t)(r0 + r) * C + c0 + c4];
  T[r][c4 + 0] = v.x; T[r][c4 + 1] = v.y;
  T[r][c4 + 2] = v.z; T[r][c4 + 3] = v.w;
  __syncthreads();
  const int cc = t >> 3, rr4 = (t & 7) * 4;
  ushort4 o;
  o.x = f2bf(T[rr4 + 0][cc]); o.y = f2bf(T[rr4 + 1][cc]);
  o.z = f2bf(T[rr4 + 2][cc]); o.w = f2bf(T[rr4 + 3][cc]);
  *(ushort4*)&out[(size_t)(c0 + cc) * R + r0 + rr4] = o;
}

// ---------------------------------------------------------------------------
// bf16 GEMM, 2-phase double-buffered (T3 minimum recipe):
//   prologue: STAGE(buf0); barrier
//   loop:     STAGE(buf^1, t+1) issued FIRST, then ds_read+MFMA on buf,
//             then one __syncthreads (= vmcnt(0)+lgkmcnt(0)+barrier)
// -> next-tile HBM latency hides under this tile's MFMA; one barrier per
//    K-step instead of two.
// V_SPLIT: for the QKV GEMM, blocks with n0 >= 2048 hold the V projection;
// write it TRANSPOSED straight to vt[bh][d][token] (ushort4 = 4 consecutive
// tokens per lane) and skip the qkvb store -> vtrans kernel eliminated.
// ---------------------------------------------------------------------------
template <int BM, int BN, bool OUT_BF16, bool V_SPLIT>
__global__ __launch_bounds__(256) void gemm_bt(
    const ushort* __restrict__ A, const ushort* __restrict__ Bt,
    const float* __restrict__ bias, void* __restrict__ Cout,
    ushort* __restrict__ vt, int M, int N, int K) {
  constexpr int TM = BM / 32, TN = BN / 32;
  __shared__ ushort As[2][BM * 32];
  __shared__ ushort Bs[2][BN * 32];
  const int tid = threadIdx.x;
  const int wv = tid >> 6, lane = tid & 63;
  const int l15 = lane & 15, quad = lane >> 4;
  const int ln4 = lane >> 2, kp = (lane & 3) * 8;
  const int m0 = blockIdx.y * BM, n0 = blockIdx.x * BN;
  const int wrow = (wv >> 1) * (BM / 2), wcol = (wv & 1) * (BN / 2);

  const ushort* Arow = &A[(size_t)(m0 + wv * 16 + ln4) * K + kp];
  const ushort* Brow = &Bt[(size_t)(n0 + wv * 16 + ln4) * K + kp];

  f32x4 acc[TM][TN] = {};

  // prologue stage of tile 0
#pragma unroll
  for (int u = 0; u < BM / 64; u++)
    gl_lds16(Arow + (size_t)u * 64 * K, &As[0][wv * 512 + u * 2048]);
#pragma unroll
  for (int u = 0; u < BN / 64; u++)
    gl_lds16(Brow + (size_t)u * 64 * K, &Bs[0][wv * 512 + u * 2048]);
  __syncthreads();

  const int nt = K / 32;
  int cur = 0;
  for (int t = 0; t < nt; ++t) {
    // issue next-tile staging BEFORE compute (overlaps with MFMA below)
    if (t + 1 < nt) {
      const int k1 = (t + 1) * 32;
#pragma unroll
      for (int u = 0; u < BM / 64; u++)
        gl_lds16(Arow + (size_t)u * 64 * K + k1,
                 &As[cur ^ 1][wv * 512 + u * 2048]);
#pragma unroll
      for (int u = 0; u < BN / 64; u++)
        gl_lds16(Brow + (size_t)u * 64 * K + k1,
                 &Bs[cur ^ 1][wv * 512 + u * 2048]);
    }
    short8 af[TM], bfr[TN];
#pragma unroll
    for (int i = 0; i < TM; i++)
      af[i] = *(const short8*)&As[cur][(wrow + i * 16 + l15) * 32 + quad * 8];
#pragma unroll
    for (int j = 0; j < TN; j++)
      bfr[j] = *(const short8*)&Bs[cur][(wcol + j * 16 + l15) * 32 + quad * 8];
#pragma unroll
    for (int i = 0; i < TM; i++)
#pragma unroll
      for (int j = 0; j < TN; j++)
        acc[i][j] = __builtin_amdgcn_mfma_f32_16x16x32_bf16(af[i], bfr[j],
                                                            acc[i][j], 0, 0, 0);
    __syncthreads();  // drains vmcnt(0)+lgkmcnt(0); next tile ready
    cur ^= 1;
  }

  if (V_SPLIT && n0 >= 2048) {
    // V projection: write transposed to vt[((b*16+h)*64+d)*1024 + token]
#pragma unroll
    for (int j = 0; j < TN; j++) {
      const int col = n0 + wcol + j * 16 + l15;   // 2048..3071
      const int cv = col - 2048;
      const int hh = cv >> 6, dd = cv & 63;
      const float bv = bias[col];
#pragma unroll
      for (int i = 0; i < TM; i++) {
        const int row0 = m0 + wrow + i * 16 + quad * 4;  // 4-aligned
        const int bidx = row0 >> 10, jt = row0 & 1023;
        ushort4 o;
        o.x = f2bf(acc[i][j][0] + bv);
        o.y = f2bf(acc[i][j][1] + bv);
        o.z = f2bf(acc[i][j][2] + bv);
        o.w = f2bf(acc[i][j][3] + bv);
        *(ushort4*)&vt[((size_t)((bidx << 4) + hh) * 64 + dd) * 1024 + jt] = o;
      }
    }
  } else {
#pragma unroll
    for (int j = 0; j < TN; j++) {
      const int col = n0 + wcol + j * 16 + l15;
      const float bv = bias[col];
#pragma unroll
      for (int i = 0; i < TM; i++) {
#pragma unroll
        for (int r = 0; r < 4; r++) {
          const int row = m0 + wrow + i * 16 + quad * 4 + r;
          const float v = acc[i][j][r] + bv;
          if (OUT_BF16)
            ((ushort*)Cout)[(size_t)row * N + col] = f2bf(v);
          else
            ((float*)Cout)[(size_t)row * N + col] = v;
        }
      }
    }
  }
}

// ---------------------------------------------------------------------------
// MFMA attention (round-2 best-measured version). grid (S/16, B*H),
// block 256 = 4 waves. Shuffle-tree softmax reductions; XCD swizzle pins
// 8 heads per XCD (~3 MB working set < 4 MB per-XCD L2).
// ---------------------------------------------------------------------------
__global__ __launch_bounds__(256) void attn_mfma(
    const ushort* __restrict__ qkvb,  // [4096][3072] bf16 (Q,K thirds valid)
    const ushort* __restrict__ vt,    // [64][64][1024] bf16
    const float* __restrict__ mask,   // [4][1024]
    float* __restrict__ w_out,        // [64][1024][1024]
    ushort* __restrict__ ab) {        // [4096][1024] bf16 merged heads
  constexpr int LDP = 1032;
  __shared__ ushort Ps[16 * LDP];   // probs bf16, 33 KB
  __shared__ float PM[16][4];       // per-row per-wave maxes
  __shared__ float PSum[16][4];     // per-row per-wave sums

  // XCD swizzle (grid is 64 x 64 = 4096 blocks, x fastest in dispatch order)
  const int f = blockIdx.y * 64 + blockIdx.x;
  const int swz = (f & 7) * 512 + (f >> 3);
  const int qt = swz & 63, bh = swz >> 6;

  const int b = bh >> 4, h = bh & 15;
  const int q0 = qt * 16;
  const int tid = threadIdx.x;
  const int wv = tid >> 6, lane = tid & 63;
  const int l15 = lane & 15, quad = lane >> 4;

  // Q fragments (A operand: m = l15, k = quad*8+j)
  const size_t rowQ = (size_t)((b << 10) + q0 + l15) * 3072 + h * 64;
  const short8 qf0 = *(const short8*)&qkvb[rowQ + quad * 8];
  const short8 qf1 = *(const short8*)&qkvb[rowQ + 32 + quad * 8];

  float sreg[16][4];

  // ---- scores ----
#pragma unroll
  for (int i = 0; i < 16; i++) {
    const int j0 = (wv + 4 * i) * 16;
    const int col = j0 + l15;
    const float mv = mask[(b << 10) + col];
    if (j0 <= q0 + 15) {
      const size_t rowK = (size_t)((b << 10) + j0 + l15) * 3072 + 1024 + h * 64;
      const short8 kf0 = *(const short8*)&qkvb[rowK + quad * 8];
      const short8 kf1 = *(const short8*)&qkvb[rowK + 32 + quad * 8];
      f32x4 c = {0.f, 0.f, 0.f, 0.f};
      c = __builtin_amdgcn_mfma_f32_16x16x32_bf16(qf0, kf0, c, 0, 0, 0);
      c = __builtin_amdgcn_mfma_f32_16x16x32_bf16(qf1, kf1, c, 0, 0, 0);
#pragma unroll
      for (int r = 0; r < 4; r++)
        sreg[i][r] =
            (col <= q0 + quad * 4 + r ? c[r] * 0.125f : -10000.0f) + mv;
    } else {
#pragma unroll
      for (int r = 0; r < 4; r++) sreg[i][r] = -10000.0f + mv;
    }
  }

  // ---- row max: register -> intra-quad shuffle tree -> cross-wave LDS ----
#pragma unroll
  for (int r = 0; r < 4; r++) {
    float m = sreg[0][r];
#pragma unroll
    for (int i = 1; i < 16; i++) m = fmaxf(m, sreg[i][r]);
#pragma unroll
    for (int off = 1; off < 16; off <<= 1) m = fmaxf(m, __shfl_xor(m, off));
    if (l15 == 0) PM[quad * 4 + r][wv] = m;
  }
  __syncthreads();

  float mrow[4];
#pragma unroll
  for (int r = 0; r < 4; r++) {
    const f32x4 pm4 = *(const f32x4*)&PM[quad * 4 + r][0];
    mrow[r] = fmaxf(fmaxf(pm4[0], pm4[1]), fmaxf(pm4[2], pm4[3]));
  }

  // ---- exp (clamped) + row sum (same reduction shape) ----
  float psum[4] = {0.f, 0.f, 0.f, 0.f};
#pragma unroll
  for (int i = 0; i < 16; i++)
#pragma unroll
    for (int r = 0; r < 4; r++) {
      const float e = __expf(fminf(sreg[i][r] - mrow[r], 0.0f));
      sreg[i][r] = e;
      psum[r] += e;
    }
#pragma unroll
  for (int r = 0; r < 4; r++) {
    float s = psum[r];
#pragma unroll
    for (int off = 1; off < 16; off <<= 1) s += __shfl_xor(s, off);
    if (l15 == 0) PSum[quad * 4 + r][wv] = s;
  }
  __syncthreads();

  float inv4[4];
#pragma unroll
  for (int r = 0; r < 4; r++) {
    const f32x4 ps4 = *(const f32x4*)&PSum[quad * 4 + r][0];
    inv4[r] = 1.0f / fmaxf(ps4[0] + ps4[1] + ps4[2] + ps4[3], 1e-30f);
  }

  // ---- write w (fp32) + stash probs bf16 into LDS ----
#pragma unroll
  for (int i = 0; i < 16; i++) {
    const int j0 = (wv + 4 * i) * 16;
#pragma unroll
    for (int r = 0; r < 4; r++) {
      const float p = sreg[i][r] * inv4[r];
      w_out[((size_t)(bh << 10) + q0 + quad * 4 + r) * 1024 + j0 + l15] = p;
      Ps[(quad * 4 + r) * LDP + j0 + l15] = f2bf(p);
    }
  }
  __syncthreads();

  // ---- PV: A = Ps (A-frag m=l15, k=quad*8+j), B = Vt[bh][d][key] ----
  f32x4 oacc = {0.f, 0.f, 0.f, 0.f};
  const int nch = (q0 + 16 + 31) >> 5;
  const ushort* vbase = vt + ((size_t)bh * 64 + wv * 16 + l15) * 1024;
  for (int c = 0; c < nch; c++) {
    const int k0 = c * 32;
    const short8 pf = *(const short8*)&Ps[l15 * LDP + k0 + quad * 8];
    const short8 vf = *(const short8*)&vbase[k0 + quad * 8];
    oacc = __builtin_amdgcn_mfma_f32_16x16x32_bf16(pf, vf, oacc, 0, 0, 0);
  }
#pragma unroll
  for (int r = 0; r < 4; r++) {
    ab[(size_t)((b << 10) + q0 + quad * 4 + r) * 1024 + h * 64 + wv * 16 +
       l15] = f2bf(oacc[r]);
  }
}

// ---------------------------------------------------------------------------
extern "C" void kernel_launch(void* const* d_in, const int* in_sizes, int n_in,
                              void* d_out, int out_size, void* d_ws,
                              size_t ws_size, hipStream_t stream) {
  const float* x = (const float*)d_in[0];
  const float* mask = (const float*)d_in[1];
  const float* w_attn = (const float*)d_in[2];
  const float* b_attn = (const float*)d_in[3];
  const float* w_proj = (const float*)d_in[4];
  const float* b_proj = (const float*)d_in[5];

  float* out_a = (float*)d_out;                 // [4,1024,1024]
  float* out_w = out_a + (size_t)Bb * Ss * Dd;  // [4,16,1024,1024]

  char* ws = (char*)d_ws;
  ushort* xb   = (ushort*)(ws);                  //  8 MB
  ushort* wta  = (ushort*)(ws + (8u << 20));     //  6 MB
  ushort* wtp  = (ushort*)(ws + (14u << 20));    //  2 MB
  ushort* qkvb = (ushort*)(ws + (16u << 20));    // 24 MB (V third unused)
  ushort* vt   = (ushort*)(ws + (40u << 20));    //  8 MB
  ushort* ab   = (ushort*)(ws + (48u << 20));    //  8 MB

  cast_f32_bf16<<<(Bb * Ss * Dd) / 1024, 256, 0, stream>>>(x, xb);
  transpose_cast<<<dim3(3 * Dd / 32, Dd / 32), 256, 0, stream>>>(w_attn, wta,
                                                                 Dd, 3 * Dd);
  transpose_cast<<<dim3(Dd / 32, Dd / 32), 256, 0, stream>>>(w_proj, wtp, Dd,
                                                             Dd);
  // QKV GEMM: V third (n0 >= 2048) written transposed directly into vt.
  gemm_bt<128, 128, true, true><<<dim3(3 * Dd / 128, Bb * Ss / 128), 256, 0,
                                  stream>>>(xb, wta, b_attn, qkvb, vt,
                                            Bb * Ss, 3 * Dd, Dd);
  attn_mfma<<<dim3(Ss / 16, Bb * Hh), 256, 0, stream>>>(qkvb, vt, mask, out_w,
                                                        ab);
  // proj: BN=64 -> 512 blocks = 2 blocks/CU for implicit wave overlap.
  gemm_bt<128, 64, false, false><<<dim3(Dd / 64, Bb * Ss / 128), 256, 0,
                                   stream>>>(ab, wtp, b_proj, out_a, nullptr,
                                             Bb * Ss, Dd, Dd);
}